// Round 1
// baseline (722.313 us; speedup 1.0000x reference)
//
#include <hip/hip_runtime.h>

// ScaledDotProductAttention: B=4 H=12 S=2048 DK=64, fp32 in/out.
// Outputs: context [B,H,S,DK] then attn [B,H,S,S], concatenated in d_out.

#define S_LEN 2048
#define D_K   64

typedef __attribute__((ext_vector_type(8))) short short8v;   // 8 x bf16
typedef __attribute__((ext_vector_type(4))) float float4v;   // mfma acc

__device__ inline short f2bf(float f) {
    union { float f; unsigned u; } c; c.f = f;
    unsigned u = c.u;
    unsigned r = (u + 0x7FFFu + ((u >> 16) & 1u)) >> 16;  // RNE
    return (short)r;
}

// One WG: 16 query rows x all 2048 keys. 8 waves; wave w owns keys [w*256, w*256+256).
__global__ __launch_bounds__(512)
void sdpa_kernel(const float* __restrict__ Qp, const float* __restrict__ Kp,
                 const float* __restrict__ Vp, float* __restrict__ ctx,
                 float* __restrict__ attn) {
    const int qt   = blockIdx.x;   // 0..127  (q tile of 16)
    const int bh   = blockIdx.y;   // 0..47
    const int tid  = threadIdx.x;
    const int w    = tid >> 6;     // wave 0..7
    const int lane = tid & 63;
    const int lq   = lane & 15;    // col-of-tile lane index
    const int lg   = lane >> 4;    // 0..3

    const size_t base = (size_t)bh * S_LEN * D_K;
    const float* Qb = Qp + base;
    const float* Kb = Kp + base;
    const float* Vb = Vp + base;
    const int qg = qt * 16;

    __shared__ float red[16][8];        // cross-wave softmax partials
    __shared__ float ctxp[8][16][64];   // per-wave ctx partials (32 KB)
    __shared__ short pbuf[8][16][40];   // per-wave P tile, padded rows (10 KB)

    // ---- Q fragments (A operand): lane holds row qg+lq, k = step*32 + lg*8 + j
    short8v a0, a1;
    {
        const float* qr = Qb + (size_t)(qg + lq) * D_K + lg * 8;
        #pragma unroll
        for (int j = 0; j < 8; ++j) { a0[j] = f2bf(qr[j]); a1[j] = f2bf(qr[32 + j]); }
    }

    // ---- QK^T: 16 key-tiles of 16 per wave
    float4v acc[16];
    #pragma unroll
    for (int kt = 0; kt < 16; ++kt) acc[kt] = (float4v)0.0f;

    const int kw = w * 256;
    #pragma unroll
    for (int kt = 0; kt < 16; ++kt) {
        const float* kr = Kb + (size_t)(kw + kt * 16 + lq) * D_K + lg * 8;
        short8v b0, b1;
        #pragma unroll
        for (int j = 0; j < 8; ++j) { b0[j] = f2bf(kr[j]); b1[j] = f2bf(kr[32 + j]); }
        acc[kt] = __builtin_amdgcn_mfma_f32_16x16x32_bf16(a0, b0, acc[kt], 0, 0, 0);
        acc[kt] = __builtin_amdgcn_mfma_f32_16x16x32_bf16(a1, b1, acc[kt], 0, 0, 0);
    }

    // C layout: row q_local = lg*4 + r, col key = kw + kt*16 + lq.
    // ---- scale + row max (per-lane -> 16-lane group -> cross-wave via LDS)
    const float scale = 0.125f;  // 1/sqrt(64)
    float M[4], Srow[4];
    #pragma unroll
    for (int r = 0; r < 4; ++r) {
        float m = -1e30f;
        #pragma unroll
        for (int kt = 0; kt < 16; ++kt) {
            float v = acc[kt][r] * scale;
            acc[kt][r] = v;
            m = fmaxf(m, v);
        }
        #pragma unroll
        for (int off = 1; off < 16; off <<= 1) m = fmaxf(m, __shfl_xor(m, off, 64));
        M[r] = m;
    }
    if (lq == 0) {
        #pragma unroll
        for (int r = 0; r < 4; ++r) red[lg * 4 + r][w] = M[r];
    }
    __syncthreads();
    #pragma unroll
    for (int r = 0; r < 4; ++r) {
        float m = red[lg * 4 + r][0];
        #pragma unroll
        for (int ww = 1; ww < 8; ++ww) m = fmaxf(m, red[lg * 4 + r][ww]);
        M[r] = m;
    }
    __syncthreads();

    // ---- exp + row sum
    #pragma unroll
    for (int r = 0; r < 4; ++r) {
        float s = 0.f;
        #pragma unroll
        for (int kt = 0; kt < 16; ++kt) {
            float p = exp2f((acc[kt][r] - M[r]) * 1.44269504f);
            acc[kt][r] = p;
            s += p;
        }
        #pragma unroll
        for (int off = 1; off < 16; off <<= 1) s += __shfl_xor(s, off, 64);
        Srow[r] = s;
    }
    if (lq == 0) {
        #pragma unroll
        for (int r = 0; r < 4; ++r) red[lg * 4 + r][w] = Srow[r];
    }
    __syncthreads();
    #pragma unroll
    for (int r = 0; r < 4; ++r) {
        float s = 0.f;
        #pragma unroll
        for (int ww = 0; ww < 8; ++ww) s += red[lg * 4 + r][ww];
        Srow[r] = 1.0f / s;
    }

    // ---- normalize + write attn (f32)
    float* attnb = attn + (size_t)bh * S_LEN * S_LEN;
    #pragma unroll
    for (int r = 0; r < 4; ++r) {
        const size_t rowoff = (size_t)(qg + lg * 4 + r) * S_LEN + kw + lq;
        #pragma unroll
        for (int kt = 0; kt < 16; ++kt) {
            float an = acc[kt][r] * Srow[r];
            acc[kt][r] = an;
            attnb[rowoff + kt * 16] = an;
        }
    }

    // ---- PV: ctx_partial[16 x 64] per wave over its 256 keys, 32 keys/step
    float4v cacc[4];
    #pragma unroll
    for (int dt = 0; dt < 4; ++dt) cacc[dt] = (float4v)0.0f;

    for (int kt2 = 0; kt2 < 8; ++kt2) {
        #pragma unroll
        for (int t = 0; t < 2; ++t) {
            const int kt = kt2 * 2 + t;
            #pragma unroll
            for (int r = 0; r < 4; ++r)
                pbuf[w][lg * 4 + r][t * 16 + lq] = f2bf(acc[kt][r]);
        }
        __syncthreads();
        // A operand: P[q=lq][k = lg*8 + j] (32 keys of this step)
        short8v pa = *reinterpret_cast<const short8v*>(&pbuf[w][lq][lg * 8]);
        const int vkb = kw + kt2 * 32 + lg * 8;
        #pragma unroll
        for (int dt = 0; dt < 4; ++dt) {
            short8v bv;
            #pragma unroll
            for (int j = 0; j < 8; ++j)
                bv[j] = f2bf(Vb[(size_t)(vkb + j) * D_K + dt * 16 + lq]);
            cacc[dt] = __builtin_amdgcn_mfma_f32_16x16x32_bf16(pa, bv, cacc[dt], 0, 0, 0);
        }
        __syncthreads();
    }

    // ---- stash per-wave partials, reduce across waves, write ctx
    #pragma unroll
    for (int dt = 0; dt < 4; ++dt)
        #pragma unroll
        for (int r = 0; r < 4; ++r)
            ctxp[w][lg * 4 + r][dt * 16 + lq] = cacc[dt][r];
    __syncthreads();

    float* ctxb = ctx + (size_t)bh * S_LEN * D_K;
    for (int idx = tid; idx < 16 * 64; idx += 512) {
        const int q = idx >> 6, d = idx & 63;
        float s = 0.f;
        #pragma unroll
        for (int ww = 0; ww < 8; ++ww) s += ctxp[ww][q][d];
        ctxb[(size_t)(qg + q) * D_K + d] = s;
    }
}

extern "C" void kernel_launch(void* const* d_in, const int* in_sizes, int n_in,
                              void* d_out, int out_size, void* d_ws, size_t ws_size,
                              hipStream_t stream) {
    const float* Q = (const float*)d_in[0];
    const float* K = (const float*)d_in[1];
    const float* V = (const float*)d_in[2];
    float* out  = (float*)d_out;
    float* ctx  = out;                                   // 4*12*2048*64
    float* attn = out + (size_t)4 * 12 * 2048 * 64;      // 4*12*2048*2048
    dim3 grid(128, 48);
    sdpa_kernel<<<grid, 512, 0, stream>>>(Q, K, V, ctx, attn);
}

// Round 2
// 684.889 us; speedup vs baseline: 1.0546x; 1.0546x over previous
//
#include <hip/hip_runtime.h>

// ScaledDotProductAttention: B=4 H=12 S=2048 DK=64, fp32 in/out.
// d_out = context [B,H,S,DK] then attn [B,H,S,S], concatenated.

#define S_LEN 2048
#define D_K   64
#define NBH   48

typedef __attribute__((ext_vector_type(8))) short short8v;   // 8 x bf16 (4 VGPR)
typedef __attribute__((ext_vector_type(4))) float float4v;

__device__ inline unsigned short f2bf(float f) {
    union { float f; unsigned u; } c; c.f = f;
    unsigned u = c.u;
    return (unsigned short)((u + 0x7FFFu + ((u >> 16) & 1u)) >> 16);  // RNE
}

// ---------------- prepass: K f32 -> bf16 (same layout) ----------------
__global__ __launch_bounds__(256)
void conv_k_kernel(const float* __restrict__ K, unsigned short* __restrict__ Kbf) {
    const size_t N = (size_t)NBH * S_LEN * D_K;
    for (size_t i = ((size_t)blockIdx.x * 256 + threadIdx.x) * 4; i < N;
         i += (size_t)gridDim.x * 256 * 4) {
        float4v v = *reinterpret_cast<const float4v*>(K + i);
        unsigned p0 = (unsigned)f2bf(v[0]) | ((unsigned)f2bf(v[1]) << 16);
        unsigned p1 = (unsigned)f2bf(v[2]) | ((unsigned)f2bf(v[3]) << 16);
        uint2 pk; pk.x = p0; pk.y = p1;
        *reinterpret_cast<uint2*>(Kbf + i) = pk;
    }
}

// ---------------- prepass: V [bh][k][d] f32 -> VT [bh][d][k] bf16 ----------------
__global__ __launch_bounds__(256)
void trans_v_kernel(const float* __restrict__ V, unsigned short* __restrict__ VT) {
    const int bh = blockIdx.y;
    const int k0 = blockIdx.x * 64;
    __shared__ unsigned short tile[64][66];
    const int t = threadIdx.x;
    {
        const int kr = t >> 2, dq = t & 3;
        const float* src = V + (size_t)bh * S_LEN * D_K + (size_t)(k0 + kr) * D_K + dq * 16;
        #pragma unroll
        for (int i = 0; i < 4; ++i) {
            float4v v = *reinterpret_cast<const float4v*>(src + i * 4);
            #pragma unroll
            for (int j = 0; j < 4; ++j) tile[kr][dq * 16 + i * 4 + j] = f2bf(v[j]);
        }
    }
    __syncthreads();
    {
        const int d = t >> 2, kq = t & 3;
        unsigned pk[8];
        #pragma unroll
        for (int i = 0; i < 8; ++i) {
            unsigned lo = tile[kq * 16 + 2 * i][d];
            unsigned hi = tile[kq * 16 + 2 * i + 1][d];
            pk[i] = lo | (hi << 16);
        }
        unsigned* dst = reinterpret_cast<unsigned*>(
            VT + (size_t)bh * D_K * S_LEN + (size_t)d * S_LEN + k0 + kq * 16);
        uint4 a; a.x = pk[0]; a.y = pk[1]; a.z = pk[2]; a.w = pk[3];
        uint4 b; b.x = pk[4]; b.y = pk[5]; b.z = pk[6]; b.w = pk[7];
        reinterpret_cast<uint4*>(dst)[0] = a;
        reinterpret_cast<uint4*>(dst)[1] = b;
    }
}

// ---------------- main fused kernel ----------------
// WG = 16 q rows x all 2048 keys. 8 waves; wave w owns keys [w*256, w*256+256).
// Swapped QK^T: acc = mfma(A=K, B=Q) -> lane holds P[q=lq][k = kt*16 + lg*4 + r].
template <bool USE_WS>
__global__ __launch_bounds__(512)
void sdpa_kernel(const float* __restrict__ Qp, const float* __restrict__ Kp,
                 const float* __restrict__ Vp,
                 const unsigned short* __restrict__ Kbf,
                 const unsigned short* __restrict__ VT,
                 float* __restrict__ ctx, float* __restrict__ attn) {
    const int qt   = blockIdx.x;   // 0..127
    const int bh   = blockIdx.y;   // 0..47
    const int tid  = threadIdx.x;
    const int w    = tid >> 6;
    const int lane = tid & 63;
    const int lq   = lane & 15;
    const int lg   = lane >> 4;
    const int qg   = qt * 16;
    const int kw   = w * 256;
    const size_t base = (size_t)bh * S_LEN * D_K;

    // pbuf (PV staging, per-wave, half of keys at a time) unions with ctxp (epilogue)
    __shared__ __align__(16) char smem_raw[8 * 16 * 136 * 2];  // 34816 B
    __shared__ float red[16][8];
    auto pbuf = reinterpret_cast<unsigned short(*)[16][136]>(smem_raw);
    auto ctxp = reinterpret_cast<float(*)[16][64]>(smem_raw);

    // ---- Q B-fragment: lane holds query col lq, dk rows lg*8+j (two K=32 halves)
    short8v q0, q1;
    {
        const float* qr = Qp + base + (size_t)(qg + lq) * D_K + lg * 8;
        float4v qa = *reinterpret_cast<const float4v*>(qr);
        float4v qb = *reinterpret_cast<const float4v*>(qr + 4);
        float4v qc = *reinterpret_cast<const float4v*>(qr + 32);
        float4v qd = *reinterpret_cast<const float4v*>(qr + 36);
        #pragma unroll
        for (int j = 0; j < 4; ++j) {
            q0[j]     = (short)f2bf(qa[j]);
            q0[4 + j] = (short)f2bf(qb[j]);
            q1[j]     = (short)f2bf(qc[j]);
            q1[4 + j] = (short)f2bf(qd[j]);
        }
    }

    // ---- QK^T (swapped): 16 key-tiles of 16 per wave
    float4v acc[16];
    #pragma unroll
    for (int kt = 0; kt < 16; ++kt) acc[kt] = (float4v)0.0f;

    #pragma unroll
    for (int kt = 0; kt < 16; ++kt) {
        short8v k0, k1;
        if (USE_WS) {
            const unsigned short* kr = Kbf + base + (size_t)(kw + kt * 16 + lq) * D_K + lg * 8;
            k0 = *reinterpret_cast<const short8v*>(kr);
            k1 = *reinterpret_cast<const short8v*>(kr + 32);
        } else {
            const float* kr = Kp + base + (size_t)(kw + kt * 16 + lq) * D_K + lg * 8;
            float4v ka = *reinterpret_cast<const float4v*>(kr);
            float4v kb = *reinterpret_cast<const float4v*>(kr + 4);
            float4v kc = *reinterpret_cast<const float4v*>(kr + 32);
            float4v kd = *reinterpret_cast<const float4v*>(kr + 36);
            #pragma unroll
            for (int j = 0; j < 4; ++j) {
                k0[j]     = (short)f2bf(ka[j]);
                k0[4 + j] = (short)f2bf(kb[j]);
                k1[j]     = (short)f2bf(kc[j]);
                k1[4 + j] = (short)f2bf(kd[j]);
            }
        }
        acc[kt] = __builtin_amdgcn_mfma_f32_16x16x32_bf16(k0, q0, acc[kt], 0, 0, 0);
        acc[kt] = __builtin_amdgcn_mfma_f32_16x16x32_bf16(k1, q1, acc[kt], 0, 0, 0);
    }

    // ---- softmax over raw scores; fold scale into exp2 constant
    // All 64 values in a lane belong to query q = lq.
    float m = -1e30f;
    #pragma unroll
    for (int kt = 0; kt < 16; ++kt)
        #pragma unroll
        for (int r = 0; r < 4; ++r) m = fmaxf(m, acc[kt][r]);
    m = fmaxf(m, __shfl_xor(m, 16, 64));
    m = fmaxf(m, __shfl_xor(m, 32, 64));
    if (lane < 16) red[lane][w] = m;
    __syncthreads();
    float gm = red[lq][0];
    #pragma unroll
    for (int ww = 1; ww < 8; ++ww) gm = fmaxf(gm, red[lq][ww]);
    __syncthreads();

    const float C = 0.18033688011112042f;  // (1/sqrt(64)) * log2(e)
    float s = 0.f;
    #pragma unroll
    for (int kt = 0; kt < 16; ++kt)
        #pragma unroll
        for (int r = 0; r < 4; ++r) {
            float p = exp2f((acc[kt][r] - gm) * C);
            acc[kt][r] = p;
            s += p;
        }
    s += __shfl_xor(s, 16, 64);
    s += __shfl_xor(s, 32, 64);
    if (lane < 16) red[lane][w] = s;
    __syncthreads();
    float gs = red[lq][0];
    #pragma unroll
    for (int ww = 1; ww < 8; ++ww) gs += red[lq][ww];
    const float rs = 1.0f / gs;

    // ---- attn write (dwordx4), P pack to LDS, PV — two halves of 128 keys
    float* attnb = attn + (size_t)bh * S_LEN * S_LEN;
    float4v cacc[4];
    #pragma unroll
    for (int dt = 0; dt < 4; ++dt) cacc[dt] = (float4v)0.0f;

    #pragma unroll
    for (int half = 0; half < 2; ++half) {
        #pragma unroll
        for (int kth = 0; kth < 8; ++kth) {
            const int kt = half * 8 + kth;
            float4v an = acc[kt] * rs;
            *reinterpret_cast<float4v*>(
                &attnb[(size_t)(qg + lq) * S_LEN + kw + kt * 16 + lg * 4]) = an;
            unsigned p01 = (unsigned)f2bf(an[0]) | ((unsigned)f2bf(an[1]) << 16);
            unsigned p23 = (unsigned)f2bf(an[2]) | ((unsigned)f2bf(an[3]) << 16);
            unsigned* dst = reinterpret_cast<unsigned*>(&pbuf[w][lq][kth * 16 + lg * 4]);
            dst[0] = p01;
            dst[1] = p23;
        }
        // pbuf is wave-private: wave-synchronous LDS ordering, no __syncthreads needed.
        #pragma unroll
        for (int s2 = 0; s2 < 4; ++s2) {
            short8v pa = *reinterpret_cast<const short8v*>(&pbuf[w][lq][s2 * 32 + lg * 8]);
            const int kk = kw + half * 128 + s2 * 32 + lg * 8;
            #pragma unroll
            for (int dt = 0; dt < 4; ++dt) {
                short8v bv;
                if (USE_WS) {
                    bv = *reinterpret_cast<const short8v*>(
                        VT + base + (size_t)(dt * 16 + lq) * S_LEN + kk);
                } else {
                    #pragma unroll
                    for (int j = 0; j < 8; ++j)
                        bv[j] = (short)f2bf(Vp[base + (size_t)(kk + j) * D_K + dt * 16 + lq]);
                }
                cacc[dt] = __builtin_amdgcn_mfma_f32_16x16x32_bf16(pa, bv, cacc[dt], 0, 0, 0);
            }
        }
    }

    // ---- cross-wave ctx reduce (ctxp aliases pbuf: barrier first)
    __syncthreads();
    #pragma unroll
    for (int dt = 0; dt < 4; ++dt)
        #pragma unroll
        for (int r = 0; r < 4; ++r)
            ctxp[w][lg * 4 + r][dt * 16 + lq] = cacc[dt][r];
    __syncthreads();

    float* ctxb = ctx + base;
    for (int idx = tid; idx < 16 * 64; idx += 512) {
        const int q = idx >> 6, d = idx & 63;
        float sum = 0.f;
        #pragma unroll
        for (int ww = 0; ww < 8; ++ww) sum += ctxp[ww][q][d];
        ctxb[(size_t)(qg + q) * D_K + d] = sum;
    }
}

extern "C" void kernel_launch(void* const* d_in, const int* in_sizes, int n_in,
                              void* d_out, int out_size, void* d_ws, size_t ws_size,
                              hipStream_t stream) {
    const float* Q = (const float*)d_in[0];
    const float* K = (const float*)d_in[1];
    const float* V = (const float*)d_in[2];
    float* ctx  = (float*)d_out;
    float* attn = ctx + (size_t)NBH * S_LEN * D_K;

    const size_t nel  = (size_t)NBH * S_LEN * D_K;   // 6,291,456
    const size_t need = nel * 2 * 2;                 // Kbf + VT, bf16
    dim3 grid(128, 48);

    if (ws_size >= need) {
        unsigned short* Kbf = (unsigned short*)d_ws;
        unsigned short* VT  = Kbf + nel;
        conv_k_kernel<<<2048, 256, 0, stream>>>(K, Kbf);
        trans_v_kernel<<<dim3(32, 48), 256, 0, stream>>>(V, VT);
        sdpa_kernel<true><<<grid, 512, 0, stream>>>(Q, K, V, Kbf, VT, ctx, attn);
    } else {
        sdpa_kernel<false><<<grid, 512, 0, stream>>>(Q, K, V, nullptr, nullptr, ctx, attn);
    }
}

// Round 3
// 675.500 us; speedup vs baseline: 1.0693x; 1.0139x over previous
//
#include <hip/hip_runtime.h>

// ScaledDotProductAttention: B=4 H=12 S=2048 DK=64, fp32 in/out.
// d_out = context [B,H,S,DK] then attn [B,H,S,S], concatenated.

#define S_LEN 2048
#define D_K   64
#define NBH   48

typedef __attribute__((ext_vector_type(8))) short short8v;   // 8 x bf16 (4 VGPR)
typedef __attribute__((ext_vector_type(4))) float float4v;

__device__ inline unsigned short f2bf(float f) {
    union { float f; unsigned u; } c; c.f = f;
    unsigned u = c.u;
    return (unsigned short)((u + 0x7FFFu + ((u >> 16) & 1u)) >> 16);  // RNE
}

// ---------------- prepass: K f32 -> bf16 (same layout) ----------------
__global__ __launch_bounds__(256)
void conv_k_kernel(const float* __restrict__ K, unsigned short* __restrict__ Kbf) {
    const size_t N = (size_t)NBH * S_LEN * D_K;
    for (size_t i = ((size_t)blockIdx.x * 256 + threadIdx.x) * 4; i < N;
         i += (size_t)gridDim.x * 256 * 4) {
        float4v v = *reinterpret_cast<const float4v*>(K + i);
        unsigned p0 = (unsigned)f2bf(v[0]) | ((unsigned)f2bf(v[1]) << 16);
        unsigned p1 = (unsigned)f2bf(v[2]) | ((unsigned)f2bf(v[3]) << 16);
        uint2 pk; pk.x = p0; pk.y = p1;
        *reinterpret_cast<uint2*>(Kbf + i) = pk;
    }
}

// ---------------- prepass: V [bh][k][d] f32 -> VT [bh][d][k] bf16 ----------------
__global__ __launch_bounds__(256)
void trans_v_kernel(const float* __restrict__ V, unsigned short* __restrict__ VT) {
    const int bh = blockIdx.y;
    const int k0 = blockIdx.x * 64;
    __shared__ unsigned short tile[64][66];
    const int t = threadIdx.x;
    {
        const int kr = t >> 2, dq = t & 3;
        const float* src = V + (size_t)bh * S_LEN * D_K + (size_t)(k0 + kr) * D_K + dq * 16;
        #pragma unroll
        for (int i = 0; i < 4; ++i) {
            float4v v = *reinterpret_cast<const float4v*>(src + i * 4);
            #pragma unroll
            for (int j = 0; j < 4; ++j) tile[kr][dq * 16 + i * 4 + j] = f2bf(v[j]);
        }
    }
    __syncthreads();
    {
        const int d = t >> 2, kq = t & 3;
        unsigned pk[8];
        #pragma unroll
        for (int i = 0; i < 8; ++i) {
            unsigned lo = tile[kq * 16 + 2 * i][d];
            unsigned hi = tile[kq * 16 + 2 * i + 1][d];
            pk[i] = lo | (hi << 16);
        }
        unsigned* dst = reinterpret_cast<unsigned*>(
            VT + (size_t)bh * D_K * S_LEN + (size_t)d * S_LEN + k0 + kq * 16);
        uint4 a; a.x = pk[0]; a.y = pk[1]; a.z = pk[2]; a.w = pk[3];
        uint4 b; b.x = pk[4]; b.y = pk[5]; b.z = pk[6]; b.w = pk[7];
        reinterpret_cast<uint4*>(dst)[0] = a;
        reinterpret_cast<uint4*>(dst)[1] = b;
    }
}

// ---------------- main fused kernel ----------------
// WG = 16 q rows x all 2048 keys. 8 waves; wave w owns keys [w*256, w*256+256).
// Swapped QK^T: acc = mfma(A=K, B=Q) -> lane holds P[q=lq][k = kt*16 + lg*4 + r].
// Store order matters: ALL attn stores are issued at the very end (after the
// last barrier) so no vmcnt wait inside the kernel ever drains them.
template <bool USE_WS>
__global__ __launch_bounds__(512)
void sdpa_kernel(const float* __restrict__ Qp, const float* __restrict__ Kp,
                 const float* __restrict__ Vp,
                 const unsigned short* __restrict__ Kbf,
                 const unsigned short* __restrict__ VT,
                 float* __restrict__ ctx, float* __restrict__ attn) {
    const int qt   = blockIdx.x;   // 0..127
    const int bh   = blockIdx.y;   // 0..47
    const int tid  = threadIdx.x;
    const int w    = tid >> 6;
    const int lane = tid & 63;
    const int lq   = lane & 15;
    const int lg   = lane >> 4;
    const int qg   = qt * 16;
    const int kw   = w * 256;
    const size_t base = (size_t)bh * S_LEN * D_K;

    // pbuf (PV staging, per-wave) unions with ctxp (epilogue)
    __shared__ __align__(16) char smem_raw[8 * 16 * 136 * 2];  // 34816 B
    __shared__ float red_m[16][8];
    __shared__ float red_s[16][8];
    auto pbuf = reinterpret_cast<unsigned short(*)[16][136]>(smem_raw);
    auto ctxp = reinterpret_cast<float(*)[16][64]>(smem_raw);

    // ---- Q B-fragment: lane holds query col lq, dk rows lg*8+j (two K=32 halves)
    short8v q0, q1;
    {
        const float* qr = Qp + base + (size_t)(qg + lq) * D_K + lg * 8;
        float4v qa = *reinterpret_cast<const float4v*>(qr);
        float4v qb = *reinterpret_cast<const float4v*>(qr + 4);
        float4v qc = *reinterpret_cast<const float4v*>(qr + 32);
        float4v qd = *reinterpret_cast<const float4v*>(qr + 36);
        #pragma unroll
        for (int j = 0; j < 4; ++j) {
            q0[j]     = (short)f2bf(qa[j]);
            q0[4 + j] = (short)f2bf(qb[j]);
            q1[j]     = (short)f2bf(qc[j]);
            q1[4 + j] = (short)f2bf(qd[j]);
        }
    }

    // ---- QK^T (swapped): 16 key-tiles of 16 per wave
    float4v acc[16];
    #pragma unroll
    for (int kt = 0; kt < 16; ++kt) acc[kt] = (float4v)0.0f;

    #pragma unroll
    for (int kt = 0; kt < 16; ++kt) {
        short8v k0, k1;
        if (USE_WS) {
            const unsigned short* kr = Kbf + base + (size_t)(kw + kt * 16 + lq) * D_K + lg * 8;
            k0 = *reinterpret_cast<const short8v*>(kr);
            k1 = *reinterpret_cast<const short8v*>(kr + 32);
        } else {
            const float* kr = Kp + base + (size_t)(kw + kt * 16 + lq) * D_K + lg * 8;
            float4v ka = *reinterpret_cast<const float4v*>(kr);
            float4v kb = *reinterpret_cast<const float4v*>(kr + 4);
            float4v kc = *reinterpret_cast<const float4v*>(kr + 32);
            float4v kd = *reinterpret_cast<const float4v*>(kr + 36);
            #pragma unroll
            for (int j = 0; j < 4; ++j) {
                k0[j]     = (short)f2bf(ka[j]);
                k0[4 + j] = (short)f2bf(kb[j]);
                k1[j]     = (short)f2bf(kc[j]);
                k1[4 + j] = (short)f2bf(kd[j]);
            }
        }
        acc[kt] = __builtin_amdgcn_mfma_f32_16x16x32_bf16(k0, q0, acc[kt], 0, 0, 0);
        acc[kt] = __builtin_amdgcn_mfma_f32_16x16x32_bf16(k1, q1, acc[kt], 0, 0, 0);
    }

    // ---- softmax over raw scores; fold scale into exp2 constant
    float m = -1e30f;
    #pragma unroll
    for (int kt = 0; kt < 16; ++kt)
        #pragma unroll
        for (int r = 0; r < 4; ++r) m = fmaxf(m, acc[kt][r]);
    m = fmaxf(m, __shfl_xor(m, 16, 64));
    m = fmaxf(m, __shfl_xor(m, 32, 64));
    if (lane < 16) red_m[lane][w] = m;
    __syncthreads();
    float gm = red_m[lq][0];
    #pragma unroll
    for (int ww = 1; ww < 8; ++ww) gm = fmaxf(gm, red_m[lq][ww]);

    const float C = 0.18033688011112042f;  // (1/sqrt(64)) * log2(e)
    float s = 0.f;
    #pragma unroll
    for (int kt = 0; kt < 16; ++kt)
        #pragma unroll
        for (int r = 0; r < 4; ++r) {
            float p = exp2f((acc[kt][r] - gm) * C);
            acc[kt][r] = p;
            s += p;
        }
    s += __shfl_xor(s, 16, 64);
    s += __shfl_xor(s, 32, 64);
    if (lane < 16) red_s[lane][w] = s;
    __syncthreads();
    float gs = red_s[lq][0];
    #pragma unroll
    for (int ww = 1; ww < 8; ++ww) gs += red_s[lq][ww];
    const float rs = 1.0f / gs;

    // ---- normalize in registers (attn values now final)
    #pragma unroll
    for (int kt = 0; kt < 16; ++kt) acc[kt] = acc[kt] * rs;

    // ---- PV only (no global stores in this phase): two halves of 128 keys
    float4v cacc[4];
    #pragma unroll
    for (int dt = 0; dt < 4; ++dt) cacc[dt] = (float4v)0.0f;

    #pragma unroll
    for (int half = 0; half < 2; ++half) {
        #pragma unroll
        for (int kth = 0; kth < 8; ++kth) {
            const int kt = half * 8 + kth;
            unsigned p01 = (unsigned)f2bf(acc[kt][0]) | ((unsigned)f2bf(acc[kt][1]) << 16);
            unsigned p23 = (unsigned)f2bf(acc[kt][2]) | ((unsigned)f2bf(acc[kt][3]) << 16);
            unsigned* dst = reinterpret_cast<unsigned*>(&pbuf[w][lq][kth * 16 + lg * 4]);
            dst[0] = p01;
            dst[1] = p23;
        }
        // pbuf is wave-private: wave-synchronous LDS ordering, no __syncthreads needed.
        #pragma unroll
        for (int s2 = 0; s2 < 4; ++s2) {
            short8v pa = *reinterpret_cast<const short8v*>(&pbuf[w][lq][s2 * 32 + lg * 8]);
            const int kk = kw + half * 128 + s2 * 32 + lg * 8;
            #pragma unroll
            for (int dt = 0; dt < 4; ++dt) {
                short8v bv;
                if (USE_WS) {
                    bv = *reinterpret_cast<const short8v*>(
                        VT + base + (size_t)(dt * 16 + lq) * S_LEN + kk);
                } else {
                    #pragma unroll
                    for (int j = 0; j < 8; ++j)
                        bv[j] = (short)f2bf(Vp[base + (size_t)(kk + j) * D_K + dt * 16 + lq]);
                }
                cacc[dt] = __builtin_amdgcn_mfma_f32_16x16x32_bf16(pa, bv, cacc[dt], 0, 0, 0);
            }
        }
    }

    // ---- cross-wave ctx reduce (ctxp aliases pbuf: barrier first).
    // No global stores are outstanding here, so these barriers drain loads only.
    __syncthreads();
    #pragma unroll
    for (int dt = 0; dt < 4; ++dt)
        #pragma unroll
        for (int r = 0; r < 4; ++r)
            ctxp[w][lg * 4 + r][dt * 16 + lq] = cacc[dt][r];
    __syncthreads();

    float* ctxb = ctx + base;
    for (int idx = tid; idx < 16 * 64; idx += 512) {
        const int q = idx >> 6, d = idx & 63;
        float sum = 0.f;
        #pragma unroll
        for (int ww = 0; ww < 8; ++ww) sum += ctxp[ww][q][d];
        ctxb[(size_t)(qg + q) * D_K + d] = sum;
    }

    // ---- attn stores LAST: drain overlaps with next WG's compute
    float* attnb = attn + (size_t)bh * S_LEN * S_LEN + (size_t)(qg + lq) * S_LEN + kw + lg * 4;
    #pragma unroll
    for (int kt = 0; kt < 16; ++kt)
        *reinterpret_cast<float4v*>(attnb + kt * 16) = acc[kt];
}

extern "C" void kernel_launch(void* const* d_in, const int* in_sizes, int n_in,
                              void* d_out, int out_size, void* d_ws, size_t ws_size,
                              hipStream_t stream) {
    const float* Q = (const float*)d_in[0];
    const float* K = (const float*)d_in[1];
    const float* V = (const float*)d_in[2];
    float* ctx  = (float*)d_out;
    float* attn = ctx + (size_t)NBH * S_LEN * D_K;

    const size_t nel  = (size_t)NBH * S_LEN * D_K;   // 6,291,456
    const size_t need = nel * 2 * 2;                 // Kbf + VT, bf16
    dim3 grid(128, 48);

    if (ws_size >= need) {
        unsigned short* Kbf = (unsigned short*)d_ws;
        unsigned short* VT  = Kbf + nel;
        conv_k_kernel<<<2048, 256, 0, stream>>>(K, Kbf);
        trans_v_kernel<<<dim3(32, 48), 256, 0, stream>>>(V, VT);
        sdpa_kernel<true><<<grid, 512, 0, stream>>>(Q, K, V, Kbf, VT, ctx, attn);
    } else {
        sdpa_kernel<false><<<grid, 512, 0, stream>>>(Q, K, V, nullptr, nullptr, ctx, attn);
    }
}

// Round 4
// 583.854 us; speedup vs baseline: 1.2371x; 1.1570x over previous
//
#include <hip/hip_runtime.h>

// ScaledDotProductAttention: B=4 H=12 S=2048 DK=64, fp32 in/out.
// d_out = context [B,H,S,DK] then attn [B,H,S,S], concatenated.

#define S_LEN 2048
#define D_K   64
#define NBH   48
#define VT_STRIDE 2080   // padded V^T row (breaks 4KB channel camping)

typedef __attribute__((ext_vector_type(8))) short short8v;   // 8 x bf16 (4 VGPR)
typedef __attribute__((ext_vector_type(4))) float float4v;

__device__ inline unsigned short f2bf(float f) {
    union { float f; unsigned u; } c; c.f = f;
    unsigned u = c.u;
    return (unsigned short)((u + 0x7FFFu + ((u >> 16) & 1u)) >> 16);  // RNE
}

// ---------------- prepass: K f32 -> bf16 (same layout) ----------------
__global__ __launch_bounds__(256)
void conv_k_kernel(const float* __restrict__ K, unsigned short* __restrict__ Kbf) {
    const size_t N = (size_t)NBH * S_LEN * D_K;
    for (size_t i = ((size_t)blockIdx.x * 256 + threadIdx.x) * 4; i < N;
         i += (size_t)gridDim.x * 256 * 4) {
        float4v v = *reinterpret_cast<const float4v*>(K + i);
        unsigned p0 = (unsigned)f2bf(v[0]) | ((unsigned)f2bf(v[1]) << 16);
        unsigned p1 = (unsigned)f2bf(v[2]) | ((unsigned)f2bf(v[3]) << 16);
        uint2 pk; pk.x = p0; pk.y = p1;
        *reinterpret_cast<uint2*>(Kbf + i) = pk;
    }
}

// ---------------- prepass: V [bh][k][d] f32 -> VT [bh][d][k_pad] bf16 ----------------
__global__ __launch_bounds__(256)
void trans_v_kernel(const float* __restrict__ V, unsigned short* __restrict__ VT) {
    const int bh = blockIdx.y;
    const int k0 = blockIdx.x * 64;
    __shared__ unsigned short tile[64][66];
    const int t = threadIdx.x;
    {
        const int kr = t >> 2, dq = t & 3;
        const float* src = V + (size_t)bh * S_LEN * D_K + (size_t)(k0 + kr) * D_K + dq * 16;
        #pragma unroll
        for (int i = 0; i < 4; ++i) {
            float4v v = *reinterpret_cast<const float4v*>(src + i * 4);
            #pragma unroll
            for (int j = 0; j < 4; ++j) tile[kr][dq * 16 + i * 4 + j] = f2bf(v[j]);
        }
    }
    __syncthreads();
    {
        const int d = t >> 2, kq = t & 3;
        unsigned pk[8];
        #pragma unroll
        for (int i = 0; i < 8; ++i) {
            unsigned lo = tile[kq * 16 + 2 * i][d];
            unsigned hi = tile[kq * 16 + 2 * i + 1][d];
            pk[i] = lo | (hi << 16);
        }
        unsigned* dst = reinterpret_cast<unsigned*>(
            VT + (size_t)bh * D_K * VT_STRIDE + (size_t)d * VT_STRIDE + k0 + kq * 16);
        uint4 a; a.x = pk[0]; a.y = pk[1]; a.z = pk[2]; a.w = pk[3];
        uint4 b; b.x = pk[4]; b.y = pk[5]; b.z = pk[6]; b.w = pk[7];
        reinterpret_cast<uint4*>(dst)[0] = a;
        reinterpret_cast<uint4*>(dst)[1] = b;
    }
}

// ---------------- main fused kernel ----------------
// WG = 16 q rows x all 2048 keys. 8 waves; wave w owns keys [w*256, w*256+256).
// Swapped QK^T: acc = mfma(A=K, B=Q) -> lane holds P[q=lq][k = kt*16 + lg*4 + r].
// Epilogue transposes attn tile through LDS so every store is 1KB contiguous.
template <bool USE_WS>
__global__ __launch_bounds__(512)
void sdpa_kernel(const float* __restrict__ Qp, const float* __restrict__ Kp,
                 const float* __restrict__ Vp,
                 const unsigned short* __restrict__ Kbf,
                 const unsigned short* __restrict__ VT,
                 float* __restrict__ ctx, float* __restrict__ attn) {
    const int qt   = blockIdx.x;   // 0..127
    const int bh   = blockIdx.y;   // 0..47
    const int tid  = threadIdx.x;
    const int w    = tid >> 6;
    const int lane = tid & 63;
    const int lq   = lane & 15;
    const int lg   = lane >> 4;
    const int qg   = qt * 16;
    const int kw   = w * 256;
    const size_t base = (size_t)bh * S_LEN * D_K;

    // smem_raw: PV staging (pbuf), then ctx partials (ctxp), then attn chunks (abuf)
    __shared__ __align__(16) char smem_raw[8 * 16 * 136 * 2];  // 34816 B
    __shared__ float red_m[16][8];
    __shared__ float red_s[16][8];
    auto pbuf = reinterpret_cast<unsigned short(*)[16][136]>(smem_raw);
    auto ctxp = reinterpret_cast<float(*)[16][64]>(smem_raw);
    float* abuf = reinterpret_cast<float*>(smem_raw);          // [4][2056] f32

    // ---- Q B-fragment
    short8v q0, q1;
    {
        const float* qr = Qp + base + (size_t)(qg + lq) * D_K + lg * 8;
        float4v qa = *reinterpret_cast<const float4v*>(qr);
        float4v qb = *reinterpret_cast<const float4v*>(qr + 4);
        float4v qc = *reinterpret_cast<const float4v*>(qr + 32);
        float4v qd = *reinterpret_cast<const float4v*>(qr + 36);
        #pragma unroll
        for (int j = 0; j < 4; ++j) {
            q0[j]     = (short)f2bf(qa[j]);
            q0[4 + j] = (short)f2bf(qb[j]);
            q1[j]     = (short)f2bf(qc[j]);
            q1[4 + j] = (short)f2bf(qd[j]);
        }
    }

    // ---- QK^T (swapped): 16 key-tiles of 16 per wave
    float4v acc[16];
    #pragma unroll
    for (int kt = 0; kt < 16; ++kt) acc[kt] = (float4v)0.0f;

    #pragma unroll
    for (int kt = 0; kt < 16; ++kt) {
        short8v k0, k1;
        if (USE_WS) {
            const unsigned short* kr = Kbf + base + (size_t)(kw + kt * 16 + lq) * D_K + lg * 8;
            k0 = *reinterpret_cast<const short8v*>(kr);
            k1 = *reinterpret_cast<const short8v*>(kr + 32);
        } else {
            const float* kr = Kp + base + (size_t)(kw + kt * 16 + lq) * D_K + lg * 8;
            float4v ka = *reinterpret_cast<const float4v*>(kr);
            float4v kb = *reinterpret_cast<const float4v*>(kr + 4);
            float4v kc = *reinterpret_cast<const float4v*>(kr + 32);
            float4v kd = *reinterpret_cast<const float4v*>(kr + 36);
            #pragma unroll
            for (int j = 0; j < 4; ++j) {
                k0[j]     = (short)f2bf(ka[j]);
                k0[4 + j] = (short)f2bf(kb[j]);
                k1[j]     = (short)f2bf(kc[j]);
                k1[4 + j] = (short)f2bf(kd[j]);
            }
        }
        acc[kt] = __builtin_amdgcn_mfma_f32_16x16x32_bf16(k0, q0, acc[kt], 0, 0, 0);
        acc[kt] = __builtin_amdgcn_mfma_f32_16x16x32_bf16(k1, q1, acc[kt], 0, 0, 0);
    }

    // ---- softmax (scale folded into exp2 constant)
    float m = -1e30f;
    #pragma unroll
    for (int kt = 0; kt < 16; ++kt)
        #pragma unroll
        for (int r = 0; r < 4; ++r) m = fmaxf(m, acc[kt][r]);
    m = fmaxf(m, __shfl_xor(m, 16, 64));
    m = fmaxf(m, __shfl_xor(m, 32, 64));
    if (lane < 16) red_m[lane][w] = m;
    __syncthreads();
    float gm = red_m[lq][0];
    #pragma unroll
    for (int ww = 1; ww < 8; ++ww) gm = fmaxf(gm, red_m[lq][ww]);

    const float C = 0.18033688011112042f;  // (1/sqrt(64)) * log2(e)
    float s = 0.f;
    #pragma unroll
    for (int kt = 0; kt < 16; ++kt)
        #pragma unroll
        for (int r = 0; r < 4; ++r) {
            float p = exp2f((acc[kt][r] - gm) * C);
            acc[kt][r] = p;
            s += p;
        }
    s += __shfl_xor(s, 16, 64);
    s += __shfl_xor(s, 32, 64);
    if (lane < 16) red_s[lane][w] = s;
    __syncthreads();
    float gs = red_s[lq][0];
    #pragma unroll
    for (int ww = 1; ww < 8; ++ww) gs += red_s[lq][ww];
    const float rs = 1.0f / gs;

    #pragma unroll
    for (int kt = 0; kt < 16; ++kt) acc[kt] = acc[kt] * rs;

    // ---- PV: two halves of 128 keys
    float4v cacc[4];
    #pragma unroll
    for (int dt = 0; dt < 4; ++dt) cacc[dt] = (float4v)0.0f;

    #pragma unroll
    for (int half = 0; half < 2; ++half) {
        #pragma unroll
        for (int kth = 0; kth < 8; ++kth) {
            const int kt = half * 8 + kth;
            unsigned p01 = (unsigned)f2bf(acc[kt][0]) | ((unsigned)f2bf(acc[kt][1]) << 16);
            unsigned p23 = (unsigned)f2bf(acc[kt][2]) | ((unsigned)f2bf(acc[kt][3]) << 16);
            unsigned* dst = reinterpret_cast<unsigned*>(&pbuf[w][lq][kth * 16 + lg * 4]);
            dst[0] = p01;
            dst[1] = p23;
        }
        // pbuf is wave-private: wave-synchronous LDS ordering, no __syncthreads needed.
        #pragma unroll
        for (int s2 = 0; s2 < 4; ++s2) {
            short8v pa = *reinterpret_cast<const short8v*>(&pbuf[w][lq][s2 * 32 + lg * 8]);
            const int kk = kw + half * 128 + s2 * 32 + lg * 8;
            #pragma unroll
            for (int dt = 0; dt < 4; ++dt) {
                short8v bv;
                if (USE_WS) {
                    bv = *reinterpret_cast<const short8v*>(
                        VT + (size_t)bh * D_K * VT_STRIDE + (size_t)(dt * 16 + lq) * VT_STRIDE + kk);
                } else {
                    #pragma unroll
                    for (int j = 0; j < 8; ++j)
                        bv[j] = (short)f2bf(Vp[base + (size_t)(kk + j) * D_K + dt * 16 + lq]);
                }
                cacc[dt] = __builtin_amdgcn_mfma_f32_16x16x32_bf16(pa, bv, cacc[dt], 0, 0, 0);
            }
        }
    }

    // ---- cross-wave ctx reduce (ctxp aliases pbuf: barrier first)
    __syncthreads();
    #pragma unroll
    for (int dt = 0; dt < 4; ++dt)
        #pragma unroll
        for (int r = 0; r < 4; ++r)
            ctxp[w][lg * 4 + r][dt * 16 + lq] = cacc[dt][r];
    __syncthreads();

    float* ctxb = ctx + base;
    for (int idx = tid; idx < 16 * 64; idx += 512) {
        const int q = idx >> 6, d = idx & 63;
        float sum = 0.f;
        #pragma unroll
        for (int ww = 0; ww < 8; ++ww) sum += ctxp[ww][q][d];
        ctxb[(size_t)(qg + q) * D_K + d] = sum;
    }

    // ---- attn epilogue: LDS transpose -> 1KB-contiguous streaming stores.
    // 4 chunks of 4 rows; abuf [4][2056] f32 reuses smem_raw.
    __syncthreads();   // ctxp readers done before abuf overwrite
    const int arow  = w >> 1;   // row within chunk this wave streams
    const int ahalf = w & 1;    // which 4KB half of the row
    float* attnb = attn + (size_t)bh * S_LEN * S_LEN + (size_t)qg * S_LEN;
    #pragma unroll
    for (int c = 0; c < 4; ++c) {
        if ((lq >> 2) == c) {                 // these 16 lanes hold rows c*4..c*4+3
            float* dst = abuf + (lq & 3) * 2056 + kw + lg * 4;
            #pragma unroll
            for (int kt = 0; kt < 16; ++kt)
                *reinterpret_cast<float4v*>(dst + kt * 16) = acc[kt];
        }
        __syncthreads();
        {
            const float* src = abuf + arow * 2056 + ahalf * 1024 + lane * 4;
            float* gdst = attnb + (size_t)(c * 4 + arow) * S_LEN + ahalf * 1024 + lane * 4;
            #pragma unroll
            for (int k = 0; k < 4; ++k) {
                float4v v = *reinterpret_cast<const float4v*>(src + k * 256);
                *reinterpret_cast<float4v*>(gdst + k * 256) = v;
            }
        }
        __syncthreads();
    }
}

extern "C" void kernel_launch(void* const* d_in, const int* in_sizes, int n_in,
                              void* d_out, int out_size, void* d_ws, size_t ws_size,
                              hipStream_t stream) {
    const float* Q = (const float*)d_in[0];
    const float* K = (const float*)d_in[1];
    const float* V = (const float*)d_in[2];
    float* ctx  = (float*)d_out;
    float* attn = ctx + (size_t)NBH * S_LEN * D_K;

    const size_t nel  = (size_t)NBH * S_LEN * D_K;             // 6,291,456
    const size_t nvt  = (size_t)NBH * D_K * VT_STRIDE;         // padded VT elems
    const size_t need = (nel + nvt) * 2;                       // bf16
    dim3 grid(128, 48);

    if (ws_size >= need) {
        unsigned short* Kbf = (unsigned short*)d_ws;
        unsigned short* VT  = Kbf + nel;
        conv_k_kernel<<<2048, 256, 0, stream>>>(K, Kbf);
        trans_v_kernel<<<dim3(32, 48), 256, 0, stream>>>(V, VT);
        sdpa_kernel<true><<<grid, 512, 0, stream>>>(Q, K, V, Kbf, VT, ctx, attn);
    } else {
        sdpa_kernel<false><<<grid, 512, 0, stream>>>(Q, K, V, nullptr, nullptr, ctx, attn);
    }
}